// Round 1
// baseline (46.894 us; speedup 1.0000x reference)
//
#include <hip/hip_runtime.h>
#include <cmath>

// Problem constants (fixed by setup_inputs)
constexpr int B = 16, C = 3, H = 544, W = 960;
constexpr int DOWN = 4;
constexpr int OH = H / DOWN;   // 136
constexpr int OW = W / DOWN;   // 240

// Tiling: each block computes an 8x30 tile of the downsampled output
constexpr int TOH = 8, TOW = 30;
constexpr int MH = TOH * DOWN;   // 32  (mag rows)
constexpr int MW = TOW * DOWN;   // 120 (mag cols)
constexpr int SH = MH + 2;       // 34  (smooth rows incl. sobel halo)
constexpr int SW = MW + 2;       // 122
constexpr int GH = MH + 6;       // 38  (gray rows incl. blur+sobel halo)
constexpr int GW = MW + 6;       // 126
constexpr int NTH = OH / TOH;    // 17
constexpr int NTW = OW / TOW;    // 8

__global__ __launch_bounds__(256)
void edge_guidance_kernel(const float* __restrict__ in, float* __restrict__ out,
                          float gn0, float gn1, float gn2)
{
    __shared__ float gray[GH * GW];  // 19152 B
    __shared__ float sm[SH * SW];    // 16592 B

    const int tid = threadIdx.x;
    const int blk = blockIdx.x;
    const int tw = blk % NTW;
    const int th = (blk / NTW) % NTH;
    const int b  = blk / (NTW * NTH);

    const int mh0 = th * MH;   // mag-region row origin (global)
    const int mw0 = tw * MW;   // mag-region col origin (global)

    const float* inb = in + (size_t)b * C * H * W;

    // ---- stage 1: rgb -> gray into LDS, reflect indexing (pad<=3, all valid) ----
    for (int idx = tid; idx < GH * GW; idx += 256) {
        const int r = idx / GW;
        const int c = idx - r * GW;
        int gh = mh0 - 3 + r;
        int gw = mw0 - 3 + c;
        gh = gh < 0 ? -gh : (gh >= H ? 2 * H - 2 - gh : gh);
        gw = gw < 0 ? -gw : (gw >= W ? 2 * W - 2 - gw : gw);
        const float* p = inb + gh * W + gw;
        gray[idx] = 0.2989f * p[0] + 0.587f * p[H * W] + 0.114f * p[2 * H * W];
    }
    __syncthreads();

    // ---- stage 2: 5x5 gaussian blur into LDS; zero outside image (sobel zero-pad) ----
    const float gn[5] = {gn0, gn1, gn2, gn1, gn0};
    for (int idx = tid; idx < SH * SW; idx += 256) {
        const int sr = idx / SW;
        const int sc = idx - sr * SW;
        const int h = mh0 - 1 + sr;
        const int w = mw0 - 1 + sc;
        float v = 0.f;
        if (h >= 0 && h < H && w >= 0 && w < W) {
            #pragma unroll
            for (int i = 0; i < 5; ++i) {
                float rowsum = 0.f;
                #pragma unroll
                for (int j = 0; j < 5; ++j)
                    rowsum = fmaf(gn[j], gray[(sr + i) * GW + (sc + j)], rowsum);
                v = fmaf(gn[i], rowsum, v);
            }
        }
        sm[idx] = v;
    }
    __syncthreads();

    // ---- stage 3: sobel -> mag -> 4x4 avgpool -> sigmoid^2, one output px/thread ----
    if (tid < TOH * TOW) {
        const int orow = tid / TOW;
        const int ocol = tid - orow * TOW;

        float s[6][6];
        #pragma unroll
        for (int i = 0; i < 6; ++i)
            #pragma unroll
            for (int j = 0; j < 6; ++j)
                s[i][j] = sm[(orow * 4 + i) * SW + (ocol * 4 + j)];

        float acc = 0.f;
        #pragma unroll
        for (int i = 0; i < 4; ++i) {
            #pragma unroll
            for (int j = 0; j < 4; ++j) {
                const float a00 = s[i][j],     a01 = s[i][j + 1],     a02 = s[i][j + 2];
                const float a10 = s[i + 1][j],                        a12 = s[i + 1][j + 2];
                const float a20 = s[i + 2][j], a21 = s[i + 2][j + 1], a22 = s[i + 2][j + 2];
                const float gx = (a02 - a00) + 2.f * (a12 - a10) + (a22 - a20);
                const float gy = (a20 + 2.f * a21 + a22) - (a00 + 2.f * a01 + a02);
                acc += sqrtf(gx * gx + gy * gy + 1e-6f);
            }
        }
        const float down = acc * (1.f / 16.f);
        const float x = 5.0f * (down - 0.2f);
        const float sg = 1.f / (1.f + expf(-x));
        const size_t o = ((size_t)b * OH + (mh0 / DOWN + orow)) * OW + (mw0 / DOWN + ocol);
        out[o] = sg * sg;
    }
}

extern "C" void kernel_launch(void* const* d_in, const int* in_sizes, int n_in,
                              void* d_out, int out_size, void* d_ws, size_t ws_size,
                              hipStream_t stream) {
    const float* in = (const float*)d_in[0];
    float* out = (float*)d_out;

    // Gaussian 1D coefficients (separable: outer(g,g)/(sum g)^2), exact in double.
    const double g0 = std::exp(-4.0 / 4.5);  // exp(-x^2/(2*1.5^2)), x=2
    const double g1 = std::exp(-1.0 / 4.5);  // x=1
    const double g2 = 1.0;                   // x=0
    const double S = 2.0 * (g0 + g1) + g2;
    const float gn0 = (float)(g0 / S);
    const float gn1 = (float)(g1 / S);
    const float gn2 = (float)(g2 / S);

    dim3 grid(B * NTH * NTW);  // 2176 blocks
    dim3 block(256);
    hipLaunchKernelGGL(edge_guidance_kernel, grid, block, 0, stream,
                       in, out, gn0, gn1, gn2);
}

// Round 2
// 42.867 us; speedup vs baseline: 1.0939x; 1.0939x over previous
//
#include <hip/hip_runtime.h>
#include <cmath>

// Problem constants (fixed by setup_inputs)
constexpr int B = 16, C = 3, H = 544, W = 960;
constexpr int DOWN = 4;
constexpr int OH = H / DOWN;   // 136
constexpr int OW = W / DOWN;   // 240

// Tiling: each block computes an 8x30 tile of the downsampled output
constexpr int TOH = 8, TOW = 30;
constexpr int MH = TOH * DOWN;   // 32  (mag rows)
constexpr int MW = TOW * DOWN;   // 120 (mag cols)
constexpr int NTH = OH / TOH;    // 17
constexpr int NTW = OW / TOW;    // 8

// gray tile: 38 rows (mh0-3 .. mh0+34) x 128 cols loaded (mw0-4 .. mw0+123).
// Stride 132 so horizontal blur may read col idx up to 131 (slack cols
// 128..131 uninitialized -> only feed tmp cols 122/123, which are unused).
constexpr int GH = 38;
constexpr int GS = 132;          // floats, stride of bufA rows
constexpr int GC4 = 32;          // float4 column groups loaded per row

// tmp (horizontal blur): 38 rows x cols 0..123 (valid 0..121), stride 124
constexpr int TS = 124;
constexpr int TC4 = 31;          // float4 column groups

// sm (vertical blur) reuses bufA with stride TS: 34 rows x cols 0..123
constexpr int SMH = 34;

__global__ __launch_bounds__(256)
void edge_guidance_kernel(const float* __restrict__ in, float* __restrict__ out,
                          float gn0, float gn1, float gn2)
{
    __shared__ float bufA[GH * GS];  // gray, later reused as sm  (20064 B)
    __shared__ float bufB[GH * TS];  // horizontal-blur tmp       (18848 B)

    const int tid = threadIdx.x;
    const int blk = blockIdx.x;
    const int tw = blk % NTW;
    const int th = (blk / NTW) % NTH;
    const int b  = blk / (NTW * NTH);

    const int mh0 = th * MH;
    const int mw0 = tw * MW;
    const float* inb = in + (size_t)b * C * H * W;

    // ---- stage 1: rgb -> gray, float4 loads, reflect indexing ----
    for (int idx = tid; idx < GH * GC4; idx += 256) {
        const int r = idx >> 5;          // /32
        const int c = idx & 31;
        int gh = mh0 - 3 + r;
        gh = gh < 0 ? -gh : (gh >= H ? 2 * H - 2 - gh : gh);
        const int gwb = mw0 - 4 + 4 * c;
        float4 g;
        if (gwb >= 0 && gwb + 3 < W) {   // fast aligned path (row reflect ok)
            const float* p = inb + gh * W + gwb;
            const float4 r0 = *reinterpret_cast<const float4*>(p);
            const float4 r1 = *reinterpret_cast<const float4*>(p + H * W);
            const float4 r2 = *reinterpret_cast<const float4*>(p + 2 * H * W);
            g.x = fmaf(0.2989f, r0.x, fmaf(0.587f, r1.x, 0.114f * r2.x));
            g.y = fmaf(0.2989f, r0.y, fmaf(0.587f, r1.y, 0.114f * r2.y));
            g.z = fmaf(0.2989f, r0.z, fmaf(0.587f, r1.z, 0.114f * r2.z));
            g.w = fmaf(0.2989f, r0.w, fmaf(0.587f, r1.w, 0.114f * r2.w));
        } else {                         // col-boundary: scalar reflect
            float vals[4];
            #pragma unroll
            for (int k = 0; k < 4; ++k) {
                int gw = gwb + k;
                gw = gw < 0 ? -gw : (gw >= W ? 2 * W - 2 - gw : gw);
                const float* p = inb + gh * W + gw;
                vals[k] = fmaf(0.2989f, p[0], fmaf(0.587f, p[H * W], 0.114f * p[2 * H * W]));
            }
            g = make_float4(vals[0], vals[1], vals[2], vals[3]);
        }
        *reinterpret_cast<float4*>(&bufA[r * GS + 4 * c]) = g;
    }
    __syncthreads();

    // ---- stage 2a: horizontal 5-tap blur  (tmp[r][sc] = sum_j gn[j]*gray[r][sc+1+j]) ----
    for (int idx = tid; idx < GH * TC4; idx += 256) {
        const int r = idx / TC4;
        const int c = idx - r * TC4;
        const float* gp = &bufA[r * GS + 4 * c];
        const float4 a = *reinterpret_cast<const float4*>(gp);
        const float4 e = *reinterpret_cast<const float4*>(gp + 4);
        const float x8 = gp[8];
        float4 t;
        t.x = gn0 * a.y + gn1 * a.z + gn2 * a.w + gn1 * e.x + gn0 * e.y;
        t.y = gn0 * a.z + gn1 * a.w + gn2 * e.x + gn1 * e.y + gn0 * e.z;
        t.z = gn0 * a.w + gn1 * e.x + gn2 * e.y + gn1 * e.z + gn0 * e.w;
        t.w = gn0 * e.x + gn1 * e.y + gn2 * e.z + gn1 * e.w + gn0 * x8;
        *reinterpret_cast<float4*>(&bufB[r * TS + 4 * c]) = t;
    }
    __syncthreads();

    // ---- stage 2b: vertical 5-tap blur + zero outside image (sobel zero-pad) ----
    for (int idx = tid; idx < SMH * TC4; idx += 256) {
        const int sr = idx / TC4;
        const int c = idx - sr * TC4;
        const float* tp = &bufB[sr * TS + 4 * c];
        const float4 t0 = *reinterpret_cast<const float4*>(tp);
        const float4 t1 = *reinterpret_cast<const float4*>(tp + TS);
        const float4 t2 = *reinterpret_cast<const float4*>(tp + 2 * TS);
        const float4 t3 = *reinterpret_cast<const float4*>(tp + 3 * TS);
        const float4 t4 = *reinterpret_cast<const float4*>(tp + 4 * TS);
        float4 v;
        v.x = gn0 * t0.x + gn1 * t1.x + gn2 * t2.x + gn1 * t3.x + gn0 * t4.x;
        v.y = gn0 * t0.y + gn1 * t1.y + gn2 * t2.y + gn1 * t3.y + gn0 * t4.y;
        v.z = gn0 * t0.z + gn1 * t1.z + gn2 * t2.z + gn1 * t3.z + gn0 * t4.z;
        v.w = gn0 * t0.w + gn1 * t1.w + gn2 * t2.w + gn1 * t3.w + gn0 * t4.w;
        const int h = mh0 - 1 + sr;
        const bool rok = (h >= 0) && (h < H);
        const int wb = mw0 - 1 + 4 * c;
        v.x = (rok && wb + 0 >= 0 && wb + 0 < W) ? v.x : 0.f;
        v.y = (rok && wb + 1 >= 0 && wb + 1 < W) ? v.y : 0.f;
        v.z = (rok && wb + 2 >= 0 && wb + 2 < W) ? v.z : 0.f;
        v.w = (rok && wb + 3 >= 0 && wb + 3 < W) ? v.w : 0.f;
        *reinterpret_cast<float4*>(&bufA[sr * TS + 4 * c]) = v;  // reuse bufA as sm
    }
    __syncthreads();

    // ---- stage 3: sobel -> mag -> 4x4 avgpool -> sigmoid^2 ----
    if (tid < TOH * TOW) {
        const int orow = tid / TOW;
        const int ocol = tid - orow * TOW;

        float s[6][6];
        #pragma unroll
        for (int i = 0; i < 6; ++i) {
            const float* sp = &bufA[(orow * 4 + i) * TS + ocol * 4];
            const float4 a = *reinterpret_cast<const float4*>(sp);
            const float4 e = *reinterpret_cast<const float4*>(sp + 4);
            s[i][0] = a.x; s[i][1] = a.y; s[i][2] = a.z;
            s[i][3] = a.w; s[i][4] = e.x; s[i][5] = e.y;
        }

        float acc = 0.f;
        #pragma unroll
        for (int i = 0; i < 4; ++i) {
            #pragma unroll
            for (int j = 0; j < 4; ++j) {
                const float a00 = s[i][j],     a01 = s[i][j + 1],     a02 = s[i][j + 2];
                const float a10 = s[i + 1][j],                        a12 = s[i + 1][j + 2];
                const float a20 = s[i + 2][j], a21 = s[i + 2][j + 1], a22 = s[i + 2][j + 2];
                const float gx = (a02 - a00) + 2.f * (a12 - a10) + (a22 - a20);
                const float gy = (a20 + 2.f * a21 + a22) - (a00 + 2.f * a01 + a02);
                acc += sqrtf(gx * gx + gy * gy + 1e-6f);
            }
        }
        const float down = acc * (1.f / 16.f);
        const float x = 5.0f * (down - 0.2f);
        const float sg = 1.f / (1.f + expf(-x));
        const size_t o = ((size_t)b * OH + (th * TOH + orow)) * OW + (tw * TOW + ocol);
        out[o] = sg * sg;
    }
}

extern "C" void kernel_launch(void* const* d_in, const int* in_sizes, int n_in,
                              void* d_out, int out_size, void* d_ws, size_t ws_size,
                              hipStream_t stream) {
    const float* in = (const float*)d_in[0];
    float* out = (float*)d_out;

    // Gaussian 1D coefficients (separable: outer(g,g)/(sum g)^2), exact in double.
    const double g0 = std::exp(-4.0 / 4.5);  // x=2
    const double g1 = std::exp(-1.0 / 4.5);  // x=1
    const double g2 = 1.0;                   // x=0
    const double S = 2.0 * (g0 + g1) + g2;
    const float gn0 = (float)(g0 / S);
    const float gn1 = (float)(g1 / S);
    const float gn2 = (float)(g2 / S);

    dim3 grid(B * NTH * NTW);  // 2176 blocks
    dim3 block(256);
    hipLaunchKernelGGL(edge_guidance_kernel, grid, block, 0, stream,
                       in, out, gn0, gn1, gn2);
}